// Round 2
// baseline (964.437 us; speedup 1.0000x reference)
//
#include <hip/hip_runtime.h>
#include <hip/hip_bf16.h>
#include <cstdint>
#include <cstddef>

// ---------------- constants ----------------
// B=2 T=1024 H=4096 HK=8 HV=32 DK=64 DV=64 VPK=4
// KEY_DIM=512 VAL_DIM=2048 CONV_DIM=3072 KSZ=4
// M = B*T = 2048
// GEMM1: A[2048][4096] * W1t[5184][4096]^T -> qkvz[2048][5184]  (cols 5120.. = ba)
// GEMM2: on[2048][2048] * W2t[4096][2048]^T -> out[2048][4096] (fp32 output!)

typedef __attribute__((ext_vector_type(8))) short short8;
typedef __attribute__((ext_vector_type(4))) float f32x4;

__device__ __forceinline__ short f2bf(float f) {
  union { float f; unsigned u; } x; x.f = f;
  unsigned r = x.u + 0x7fffu + ((x.u >> 16) & 1u);
  return (short)(r >> 16);
}

// ---------------- elementwise fp32 -> bf16 ----------------
__global__ __launch_bounds__(256) void to_bf16_kernel(const float* __restrict__ x,
                                                      short* __restrict__ y) {
  int i = blockIdx.x * 256 + threadIdx.x;   // one float4 per thread
  float4 v = ((const float4*)x)[i];
  ushort4 r;
  r.x = (unsigned short)f2bf(v.x);
  r.y = (unsigned short)f2bf(v.y);
  r.z = (unsigned short)f2bf(v.z);
  r.w = (unsigned short)f2bf(v.w);
  ((ushort4*)y)[i] = r;
}

// ---------------- transpose+convert W_qkvz|W_ba -> Wt1[n][k] ----------------
__global__ __launch_bounds__(256) void transpose_w1(const float* __restrict__ Wq,
                                                    const float* __restrict__ Wba,
                                                    short* __restrict__ Wt) {
  __shared__ float tile[32][33];
  int n0 = blockIdx.x * 32;  // < 5184
  int k0 = blockIdx.y * 32;  // < 4096
  int t = threadIdx.x;
  int r = t >> 5;    // 0..7
  int c = t & 31;
#pragma unroll
  for (int i = 0; i < 4; ++i) {
    int kl = r + i * 8;
    int n = n0 + c;
    float v = (n < 5120) ? Wq[(size_t)(k0 + kl) * 5120 + n]
                         : Wba[(size_t)(k0 + kl) * 64 + (n - 5120)];
    tile[kl][c] = v;
  }
  __syncthreads();
#pragma unroll
  for (int i = 0; i < 4; ++i) {
    int nl = r + i * 8;
    int kl = c;
    Wt[(size_t)(n0 + nl) * 4096 + k0 + kl] = f2bf(tile[kl][nl]);
  }
}

// ---------------- transpose+convert W_out -> Wt2[n][k] ----------------
__global__ __launch_bounds__(256) void transpose_w2(const float* __restrict__ W,
                                                    short* __restrict__ Wt) {
  __shared__ float tile[32][33];
  int n0 = blockIdx.x * 32;  // < 4096
  int k0 = blockIdx.y * 32;  // < 2048
  int t = threadIdx.x;
  int r = t >> 5;
  int c = t & 31;
#pragma unroll
  for (int i = 0; i < 4; ++i) {
    int kl = r + i * 8;
    tile[kl][c] = W[(size_t)(k0 + kl) * 4096 + n0 + c];
  }
  __syncthreads();
#pragma unroll
  for (int i = 0; i < 4; ++i) {
    int nl = r + i * 8;
    int kl = c;
    Wt[(size_t)(n0 + nl) * 2048 + k0 + kl] = f2bf(tile[kl][nl]);
  }
}

// ---------------- bf16 MFMA GEMM: C[m][n] = sum_k A[m][k]*Bt[n][k] ----------------
template <bool OUT_BF16>
__global__ __launch_bounds__(256) void gemm_bt(const short* __restrict__ A,
                                               const short* __restrict__ Bt,
                                               void* __restrict__ Cp,
                                               int M, int N, int K) {
  __shared__ short As[64 * 32];
  __shared__ short Bs[64 * 32];
  const int tid = threadIdx.x;
  const int wave = tid >> 6;
  const int lane = tid & 63;
  const int m0 = blockIdx.x * 64;
  const int n0 = blockIdx.y * 64;
  const int lm = tid >> 2;          // 0..63 staging row
  const int lk = (tid & 3) << 3;    // 0,8,16,24 staging k
  const int fr = lane & 15;         // fragment row (m or n within 16)
  const int kq = (lane >> 4) << 3;  // fragment k offset (0,8,16,24)

  f32x4 acc[4];
#pragma unroll
  for (int i = 0; i < 4; ++i) acc[i] = (f32x4){0.f, 0.f, 0.f, 0.f};

  const short* Arow = A + (size_t)(m0 + lm) * K + lk;
  const short* Brow = Bt + (size_t)(n0 + lm) * K + lk;

  for (int k0 = 0; k0 < K; k0 += 32) {
    __syncthreads();
    *(uint4*)&As[lm * 32 + lk] = *(const uint4*)(Arow + k0);
    *(uint4*)&Bs[lm * 32 + lk] = *(const uint4*)(Brow + k0);
    __syncthreads();
    short8 af = *(const short8*)&As[(wave * 16 + fr) * 32 + kq];
#pragma unroll
    for (int nt = 0; nt < 4; ++nt) {
      short8 bf = *(const short8*)&Bs[(nt * 16 + fr) * 32 + kq];
      acc[nt] = __builtin_amdgcn_mfma_f32_16x16x32_bf16(af, bf, acc[nt], 0, 0, 0);
    }
  }
  // C/D layout: col = lane&15, row = (lane>>4)*4 + r
  const int mrow = m0 + wave * 16 + ((lane >> 4) << 2);
  const int ncol = n0 + fr;
#pragma unroll
  for (int nt = 0; nt < 4; ++nt) {
#pragma unroll
    for (int r = 0; r < 4; ++r) {
      size_t idx = (size_t)(mrow + r) * N + ncol + nt * 16;
      if (OUT_BF16)
        ((short*)Cp)[idx] = f2bf(acc[nt][r]);
      else
        ((float*)Cp)[idx] = acc[nt][r];
    }
  }
}

// ---------------- conv(4-tap causal) + silu + l2norm(q,k) ----------------
// qkvz row layout per hk group (640): q[64] k[64] v[256] z[256]; ba at col 5120+
// mix output layout: qn[512] (hk*64+d), kn[512], v[2048] (hv*64+dv)
__global__ __launch_bounds__(256) void conv_kernel(const float* __restrict__ qkvz,
                                                   const float* __restrict__ conv_w,
                                                   float* __restrict__ mix) {
  __shared__ float sq[1024];
  __shared__ float scale[16];
  int bt = blockIdx.x;       // b*1024 + t
  int t = bt & 1023;
  int tid = threadIdx.x;
  for (int c = tid; c < 3072; c += 256) {
    int col;
    if (c < 512) {
      col = (c >> 6) * 640 + (c & 63);
    } else if (c < 1024) {
      int c2 = c - 512;
      col = (c2 >> 6) * 640 + 64 + (c2 & 63);
    } else {
      int c3 = c - 1024;
      int hv = c3 >> 6;
      col = (hv >> 2) * 640 + 128 + (hv & 3) * 64 + (c3 & 63);
    }
    float acc = 0.f;
#pragma unroll
    for (int j = 0; j < 4; ++j) {
      int tt = t - 3 + j;
      if (tt >= 0) acc += qkvz[(size_t)(bt - 3 + j) * 5184 + col] * conv_w[c * 4 + j];
    }
    float sv = acc / (1.f + __expf(-acc));  // silu
    if (c < 1024)
      sq[c] = sv;
    else
      mix[(size_t)bt * 3072 + c] = sv;
  }
  __syncthreads();
  // 16 groups (8 q heads + 8 k heads) of 64: l2 norm
  int g = tid >> 4, l = tid & 15;
  float p = 0.f;
#pragma unroll
  for (int i = 0; i < 4; ++i) {
    float v = sq[g * 64 + l * 4 + i];
    p += v * v;
  }
  p += __shfl_xor(p, 1);
  p += __shfl_xor(p, 2);
  p += __shfl_xor(p, 4);
  p += __shfl_xor(p, 8);
  if (l == 0) scale[g] = rsqrtf(p + 1e-6f);
  __syncthreads();
  for (int c = tid; c < 1024; c += 256) {
    float s = scale[c >> 6] * ((c < 512) ? 0.125f : 1.f);  // q gets DK^-0.5
    mix[(size_t)bt * 3072 + c] = sq[c] * s;
  }
}

// ---------------- gates: eg = exp(g), beta = sigmoid(b) ----------------
__global__ __launch_bounds__(256) void gate_kernel(const float* __restrict__ qkvz,
                                                   const float* __restrict__ dt_bias,
                                                   const float* __restrict__ A_log,
                                                   float* __restrict__ eg,
                                                   float* __restrict__ beta) {
  int i = blockIdx.x * 256 + threadIdx.x;  // < 65536 = 2048*32
  int hv = i & 31;
  int bt = i >> 5;
  int hk = hv >> 2, vp = hv & 3;
  const float* row = qkvz + (size_t)bt * 5184 + 5120 + hk * 8;
  float bv = row[vp];
  float av = row[4 + vp];
  float x = av + dt_bias[hv];
  float sp = (x > 20.f) ? x : log1pf(expf(x));
  float g = -expf(A_log[hv]) * sp;
  eg[i] = expf(g);
  beta[i] = 1.f / (1.f + expf(-bv));
}

// ---------------- sequential delta-rule scan ----------------
// 256 blocks: (b, hv, quarter). Each block: 16 DV-columns x 64 DK-rows.
// thread: cl = tid>>4 (local col), l16 = tid&15 (row group, rows l16*4..+3)
__global__ __launch_bounds__(256) void scan_kernel(const float* __restrict__ mix,
                                                   const float* __restrict__ eg,
                                                   const float* __restrict__ beta,
                                                   float* __restrict__ o) {
  __shared__ float qs[16][64], ks[16][64], vs[16][16], egs[16], bes[16];
  int bid = blockIdx.x;
  int quarter = bid & 3;
  int hv = (bid >> 2) & 31;
  int b = bid >> 7;
  int hk = hv >> 2;
  int tid = threadIdx.x;
  int cl = tid >> 4, l16 = tid & 15;
  int vcol = quarter * 16 + cl;
  int r0 = l16 * 4;
  float s0 = 0.f, s1 = 0.f, s2 = 0.f, s3 = 0.f;

  for (int t0 = 0; t0 < 1024; t0 += 16) {
    for (int i = tid; i < 1024; i += 256) {
      int tt = i >> 6, c = i & 63;
      size_t base = (size_t)(b * 1024 + t0 + tt) * 3072;
      qs[tt][c] = mix[base + hk * 64 + c];
      ks[tt][c] = mix[base + 512 + hk * 64 + c];
    }
    {
      int tt = tid >> 4, c = tid & 15;  // 256 == 16*16
      vs[tt][c] = mix[(size_t)(b * 1024 + t0 + tt) * 3072 + 1024 + hv * 64 + quarter * 16 + c];
    }
    if (tid < 16)
      egs[tid] = eg[(b * 1024 + t0 + tid) * 32 + hv];
    else if (tid < 32)
      bes[tid - 16] = beta[(b * 1024 + t0 + tid - 16) * 32 + hv];
    __syncthreads();

    for (int tt = 0; tt < 16; ++tt) {
      float e = egs[tt], be = bes[tt];
      float4 k4 = *(const float4*)&ks[tt][r0];
      float4 q4 = *(const float4*)&qs[tt][r0];
      s0 *= e; s1 *= e; s2 *= e; s3 *= e;
      float p = s0 * k4.x + s1 * k4.y + s2 * k4.z + s3 * k4.w;
      p += __shfl_xor(p, 1);
      p += __shfl_xor(p, 2);
      p += __shfl_xor(p, 4);
      p += __shfl_xor(p, 8);
      float delta = (vs[tt][cl] - p) * be;
      s0 += k4.x * delta; s1 += k4.y * delta; s2 += k4.z * delta; s3 += k4.w * delta;
      float op = s0 * q4.x + s1 * q4.y + s2 * q4.z + s3 * q4.w;
      op += __shfl_xor(op, 1);
      op += __shfl_xor(op, 2);
      op += __shfl_xor(op, 4);
      op += __shfl_xor(op, 8);
      if (l16 == 0) o[(size_t)(b * 1024 + t0 + tt) * 2048 + hv * 64 + vcol] = op;
    }
    __syncthreads();
  }
}

// ---------------- rmsnorm * norm_w * silu(z), -> bf16 ----------------
__global__ __launch_bounds__(256) void rms_gate_kernel(const float* __restrict__ o,
                                                       const float* __restrict__ qkvz,
                                                       const float* __restrict__ norm_w,
                                                       short* __restrict__ on) {
  int row = blockIdx.x * 4 + (threadIdx.x >> 6);  // (bt*32+hv) < 65536
  int d = threadIdx.x & 63;
  int hv = row & 31;
  int bt = row >> 5;
  int hk = hv >> 2, vp = hv & 3;
  float x = o[(size_t)row * 64 + d];
  float ss = x * x;
  ss += __shfl_xor(ss, 1);
  ss += __shfl_xor(ss, 2);
  ss += __shfl_xor(ss, 4);
  ss += __shfl_xor(ss, 8);
  ss += __shfl_xor(ss, 16);
  ss += __shfl_xor(ss, 32);
  float sc = rsqrtf(ss * (1.f / 64.f) + 1e-5f);
  float z = qkvz[(size_t)bt * 5184 + hk * 640 + 384 + vp * 64 + d];
  float val = x * sc * norm_w[d] * (z / (1.f + __expf(-z)));
  on[(size_t)row * 64 + d] = f2bf(val);
}

// ---------------- launch ----------------
extern "C" void kernel_launch(void* const* d_in, const int* in_sizes, int n_in,
                              void* d_out, int out_size, void* d_ws, size_t ws_size,
                              hipStream_t stream) {
  const float* hidden = (const float*)d_in[0];
  const float* W_qkvz = (const float*)d_in[1];
  const float* W_ba = (const float*)d_in[2];
  const float* conv_w = (const float*)d_in[3];
  const float* dt_bias = (const float*)d_in[4];
  const float* A_log = (const float*)d_in[5];
  const float* norm_w = (const float*)d_in[6];
  const float* W_out = (const float*)d_in[7];
  float* out = (float*)d_out;  // fp32 output (reference output dtype is float32)

  char* ws = (char*)d_ws;
  short* A_bf = (short*)(ws + 0);                // 16,777,216 B
  short* Wt1 = (short*)(ws + 16777216);          // 42,467,328 B  [5184][4096]
  short* Wt2 = (short*)(ws + 59244544);          // 16,777,216 B  [4096][2048]
  float* qkvz = (float*)(ws + 76021760);         // 42,467,328 B  [2048][5184]
  float* mix = (float*)(ws + 118489088);         // 25,165,824 B  [2048][3072]
  float* eg = (float*)(ws + 143654912);          //    262,144 B  [2048][32]
  float* beta = (float*)(ws + 143917056);        //    262,144 B
  float* o = (float*)(ws + 144179200);           // 16,777,216 B  [2048][2048]
  short* on = (short*)(ws + 160956416);          //  8,388,608 B  [2048][2048]

  to_bf16_kernel<<<8192, 256, 0, stream>>>(hidden, A_bf);
  transpose_w1<<<dim3(162, 128), 256, 0, stream>>>(W_qkvz, W_ba, Wt1);
  transpose_w2<<<dim3(128, 64), 256, 0, stream>>>(W_out, Wt2);
  gemm_bt<false><<<dim3(32, 81), 256, 0, stream>>>(A_bf, Wt1, qkvz, 2048, 5184, 4096);
  conv_kernel<<<2048, 256, 0, stream>>>(qkvz, conv_w, mix);
  gate_kernel<<<256, 256, 0, stream>>>(qkvz, dt_bias, A_log, eg, beta);
  scan_kernel<<<256, 256, 0, stream>>>(mix, eg, beta, o);
  rms_gate_kernel<<<16384, 256, 0, stream>>>(o, qkvz, norm_w, on);
  gemm_bt<false><<<dim3(32, 64), 256, 0, stream>>>(on, Wt2, out, 2048, 4096, 2048);
}

// Round 3
// 734.714 us; speedup vs baseline: 1.3127x; 1.3127x over previous
//
#include <hip/hip_runtime.h>
#include <hip/hip_bf16.h>
#include <cstdint>
#include <cstddef>

// ---------------- constants ----------------
// B=2 T=1024 H=4096 HK=8 HV=32 DK=64 DV=64 VPK=4
// KEY_DIM=512 VAL_DIM=2048 CONV_DIM=3072 KSZ=4
// M = B*T = 2048
// GEMM1: A[2048][4096] * W1t[5184][4096]^T -> qkvz[2048][5184]  (cols 5120.. = ba)
// GEMM2: on[2048][2048] * W2t[4096][2048]^T -> out[2048][4096] (fp32 output)
// Scan: chunked delta rule, chunk C=64, units = b(2) x hv(32) x chunk(16) = 1024

typedef __attribute__((ext_vector_type(8))) short short8;
typedef __attribute__((ext_vector_type(4))) float f32x4;

__device__ __forceinline__ short f2bf(float f) {
  union { float f; unsigned u; } x; x.f = f;
  unsigned r = x.u + 0x7fffu + ((x.u >> 16) & 1u);
  return (short)(r >> 16);
}

// ---------------- elementwise fp32 -> bf16 ----------------
__global__ __launch_bounds__(256) void to_bf16_kernel(const float* __restrict__ x,
                                                      short* __restrict__ y) {
  int i = blockIdx.x * 256 + threadIdx.x;   // one float4 per thread
  float4 v = ((const float4*)x)[i];
  ushort4 r;
  r.x = (unsigned short)f2bf(v.x);
  r.y = (unsigned short)f2bf(v.y);
  r.z = (unsigned short)f2bf(v.z);
  r.w = (unsigned short)f2bf(v.w);
  ((ushort4*)y)[i] = r;
}

// ---------------- transpose+convert W_qkvz|W_ba -> Wt1[n][k] ----------------
__global__ __launch_bounds__(256) void transpose_w1(const float* __restrict__ Wq,
                                                    const float* __restrict__ Wba,
                                                    short* __restrict__ Wt) {
  __shared__ float tile[32][33];
  int n0 = blockIdx.x * 32;  // < 5184
  int k0 = blockIdx.y * 32;  // < 4096
  int t = threadIdx.x;
  int r = t >> 5;    // 0..7
  int c = t & 31;
#pragma unroll
  for (int i = 0; i < 4; ++i) {
    int kl = r + i * 8;
    int n = n0 + c;
    float v = (n < 5120) ? Wq[(size_t)(k0 + kl) * 5120 + n]
                         : Wba[(size_t)(k0 + kl) * 64 + (n - 5120)];
    tile[kl][c] = v;
  }
  __syncthreads();
#pragma unroll
  for (int i = 0; i < 4; ++i) {
    int nl = r + i * 8;
    int kl = c;
    Wt[(size_t)(n0 + nl) * 4096 + k0 + kl] = f2bf(tile[kl][nl]);
  }
}

// ---------------- transpose+convert W_out -> Wt2[n][k] ----------------
__global__ __launch_bounds__(256) void transpose_w2(const float* __restrict__ W,
                                                    short* __restrict__ Wt) {
  __shared__ float tile[32][33];
  int n0 = blockIdx.x * 32;  // < 4096
  int k0 = blockIdx.y * 32;  // < 2048
  int t = threadIdx.x;
  int r = t >> 5;
  int c = t & 31;
#pragma unroll
  for (int i = 0; i < 4; ++i) {
    int kl = r + i * 8;
    tile[kl][c] = W[(size_t)(k0 + kl) * 4096 + n0 + c];
  }
  __syncthreads();
#pragma unroll
  for (int i = 0; i < 4; ++i) {
    int nl = r + i * 8;
    int kl = c;
    Wt[(size_t)(n0 + nl) * 2048 + k0 + kl] = f2bf(tile[kl][nl]);
  }
}

// ---------------- bf16 MFMA GEMM: C[m][n] = sum_k A[m][k]*Bt[n][k] ----------------
template <bool OUT_BF16>
__global__ __launch_bounds__(256) void gemm_bt(const short* __restrict__ A,
                                               const short* __restrict__ Bt,
                                               void* __restrict__ Cp,
                                               int M, int N, int K) {
  __shared__ short As[64 * 32];
  __shared__ short Bs[64 * 32];
  const int tid = threadIdx.x;
  const int wave = tid >> 6;
  const int lane = tid & 63;
  const int m0 = blockIdx.x * 64;
  const int n0 = blockIdx.y * 64;
  const int lm = tid >> 2;          // 0..63 staging row
  const int lk = (tid & 3) << 3;    // 0,8,16,24 staging k
  const int fr = lane & 15;         // fragment row (m or n within 16)
  const int kq = (lane >> 4) << 3;  // fragment k offset (0,8,16,24)

  f32x4 acc[4];
#pragma unroll
  for (int i = 0; i < 4; ++i) acc[i] = (f32x4){0.f, 0.f, 0.f, 0.f};

  const short* Arow = A + (size_t)(m0 + lm) * K + lk;
  const short* Brow = Bt + (size_t)(n0 + lm) * K + lk;

  for (int k0 = 0; k0 < K; k0 += 32) {
    __syncthreads();
    *(uint4*)&As[lm * 32 + lk] = *(const uint4*)(Arow + k0);
    *(uint4*)&Bs[lm * 32 + lk] = *(const uint4*)(Brow + k0);
    __syncthreads();
    short8 af = *(const short8*)&As[(wave * 16 + fr) * 32 + kq];
#pragma unroll
    for (int nt = 0; nt < 4; ++nt) {
      short8 bf = *(const short8*)&Bs[(nt * 16 + fr) * 32 + kq];
      acc[nt] = __builtin_amdgcn_mfma_f32_16x16x32_bf16(af, bf, acc[nt], 0, 0, 0);
    }
  }
  // C/D layout: col = lane&15, row = (lane>>4)*4 + r
  const int mrow = m0 + wave * 16 + ((lane >> 4) << 2);
  const int ncol = n0 + fr;
#pragma unroll
  for (int nt = 0; nt < 4; ++nt) {
#pragma unroll
    for (int r = 0; r < 4; ++r) {
      size_t idx = (size_t)(mrow + r) * N + ncol + nt * 16;
      if (OUT_BF16)
        ((short*)Cp)[idx] = f2bf(acc[nt][r]);
      else
        ((float*)Cp)[idx] = acc[nt][r];
    }
  }
}

// ---------------- conv(4-tap causal) + silu + l2norm(q,k) ----------------
__global__ __launch_bounds__(256) void conv_kernel(const float* __restrict__ qkvz,
                                                   const float* __restrict__ conv_w,
                                                   float* __restrict__ mix) {
  __shared__ float sq[1024];
  __shared__ float scale[16];
  int bt = blockIdx.x;       // b*1024 + t
  int t = bt & 1023;
  int tid = threadIdx.x;
  for (int c = tid; c < 3072; c += 256) {
    int col;
    if (c < 512) {
      col = (c >> 6) * 640 + (c & 63);
    } else if (c < 1024) {
      int c2 = c - 512;
      col = (c2 >> 6) * 640 + 64 + (c2 & 63);
    } else {
      int c3 = c - 1024;
      int hv = c3 >> 6;
      col = (hv >> 2) * 640 + 128 + (hv & 3) * 64 + (c3 & 63);
    }
    float acc = 0.f;
#pragma unroll
    for (int j = 0; j < 4; ++j) {
      int tt = t - 3 + j;
      if (tt >= 0) acc += qkvz[(size_t)(bt - 3 + j) * 5184 + col] * conv_w[c * 4 + j];
    }
    float sv = acc / (1.f + __expf(-acc));  // silu
    if (c < 1024)
      sq[c] = sv;
    else
      mix[(size_t)bt * 3072 + c] = sv;
  }
  __syncthreads();
  int g = tid >> 4, l = tid & 15;
  float p = 0.f;
#pragma unroll
  for (int i = 0; i < 4; ++i) {
    float v = sq[g * 64 + l * 4 + i];
    p += v * v;
  }
  p += __shfl_xor(p, 1);
  p += __shfl_xor(p, 2);
  p += __shfl_xor(p, 4);
  p += __shfl_xor(p, 8);
  if (l == 0) scale[g] = rsqrtf(p + 1e-6f);
  __syncthreads();
  for (int c = tid; c < 1024; c += 256) {
    float s = scale[c >> 6] * ((c < 512) ? 0.125f : 1.f);  // q gets DK^-0.5
    mix[(size_t)bt * 3072 + c] = sq[c] * s;
  }
}

// ---------------- gates: g (log-decay) and beta = sigmoid(b) ----------------
__global__ __launch_bounds__(256) void gate_kernel(const float* __restrict__ qkvz,
                                                   const float* __restrict__ dt_bias,
                                                   const float* __restrict__ A_log,
                                                   float* __restrict__ gb,
                                                   float* __restrict__ beta) {
  int i = blockIdx.x * 256 + threadIdx.x;  // < 65536 = 2048*32
  int hv = i & 31;
  int bt = i >> 5;
  int hk = hv >> 2, vp = hv & 3;
  const float* row = qkvz + (size_t)bt * 5184 + 5120 + hk * 8;
  float bv = row[vp];
  float av = row[4 + vp];
  float x = av + dt_bias[hv];
  float sp = (x > 20.f) ? x : log1pf(expf(x));
  gb[i] = -expf(A_log[hv]) * sp;        // log-decay g_t (<= 0)
  beta[i] = 1.f / (1.f + expf(-bv));
}

// ---------------- chunked delta-rule precompute ----------------
// per unit u=(b,hv,chunk): builds W = M diag(beta e^c) K, R = M (beta V),
// P[t][s] = (q_t.k_s) e^{c_t-c_s} [s<=t], and stores within-chunk cumsum c.
// M = (I+A)^{-1}, A[t][s] = beta_t (k_t.k_s) e^{c_t-c_s} [s<t].
__global__ __launch_bounds__(256) void precompute_kernel(
    const float* __restrict__ mix, const float* __restrict__ gbuf,
    const float* __restrict__ betab, float* __restrict__ Wbuf,
    float* __restrict__ Pbuf, float* __restrict__ Rbuf, float* __restrict__ cbuf) {
  __shared__ float Kt[64][68];   // K col-major: Kt[d][t]; later K' row-major scaled
  __shared__ float Vb[64][68];   // V row-major
  __shared__ float AM[64][68];   // A; later Q col-major
  __shared__ float Mm[64][68];   // (I+A)^{-1}
  __shared__ float Tb[16][17];
  __shared__ float cs[64], bb[64];

  const int u = blockIdx.x;
  const int chunk = u & 15, hv = (u >> 4) & 31, b = u >> 9;
  const int hk = hv >> 2;
  const int t0g = b * 1024 + chunk * 64;
  const int tid = threadIdx.x;
  const int tr = tid >> 2, q4 = tid & 3;

  // stage K (col-major) and V (row-major)
  {
    const float* mrow = mix + (size_t)(t0g + tr) * 3072;
#pragma unroll
    for (int e = 0; e < 4; ++e) {
      int c0 = q4 * 16 + e * 4;
      float4 kv = *(const float4*)(mrow + 512 + hk * 64 + c0);
      Kt[c0 + 0][tr] = kv.x; Kt[c0 + 1][tr] = kv.y;
      Kt[c0 + 2][tr] = kv.z; Kt[c0 + 3][tr] = kv.w;
      *(float4*)&Vb[tr][c0] = *(const float4*)(mrow + 1024 + hv * 64 + c0);
    }
  }
  if (tid < 64) {
    cs[tid] = gbuf[(size_t)(t0g + tid) * 32 + hv];
    bb[tid] = betab[(size_t)(t0g + tid) * 32 + hv];
  }
  __syncthreads();
  // inclusive cumsum of g within chunk
  for (int off = 1; off < 64; off <<= 1) {
    float v = 0.f;
    if (tid < 64 && tid >= off) v = cs[tid - off];
    __syncthreads();
    if (tid < 64) cs[tid] += v;
    __syncthreads();
  }
  if (tid < 64) cbuf[(size_t)u * 64 + tid] = cs[tid];

  // KK^T -> A (strictly lower, scaled)
  {
    float acc[16];
#pragma unroll
    for (int i = 0; i < 16; ++i) acc[i] = 0.f;
    for (int d = 0; d < 64; ++d) {
      float kv = Kt[d][tr];
#pragma unroll
      for (int e = 0; e < 4; ++e) {
        float4 ks = *(const float4*)&Kt[d][q4 * 16 + e * 4];
        acc[e * 4 + 0] += kv * ks.x; acc[e * 4 + 1] += kv * ks.y;
        acc[e * 4 + 2] += kv * ks.z; acc[e * 4 + 3] += kv * ks.w;
      }
    }
    float bt_ = bb[tr], ct_ = cs[tr];
#pragma unroll
    for (int j = 0; j < 16; ++j) {
      int s = q4 * 16 + j;
      AM[tr][s] = (s < tr) ? bt_ * acc[j] * __expf(ct_ - cs[s]) : 0.f;
    }
  }
  __syncthreads();

  // M = (I+A)^{-1}: zero, diag 16x16 blocks (wave 0), then off-diag blocks
  for (int i = tid; i < 64 * 68; i += 256) (&Mm[0][0])[i] = 0.f;
  __syncthreads();
  if (tid < 64) {
    int blk = tid >> 4, j = tid & 15, base = blk * 16;
    Mm[base][base + j] = (j == 0) ? 1.f : 0.f;
    for (int r = 1; r < 16; ++r) {
      float sum = 0.f;
      for (int s = 0; s < r; ++s) sum += AM[base + r][base + s] * Mm[base + s][base + j];
      Mm[base + r][base + j] = ((r == j) ? 1.f : 0.f) - sum;
    }
  }
  __syncthreads();
  for (int d = 1; d < 4; ++d) {
    for (int j = 0; j + d < 4; ++j) {
      int i = j + d;
      int r = tid >> 4, c = tid & 15;
      float tsum = 0.f;
      for (int kb = j; kb < i; ++kb)
        for (int uu = 0; uu < 16; ++uu)
          tsum += AM[i * 16 + r][kb * 16 + uu] * Mm[kb * 16 + uu][j * 16 + c];
      Tb[r][c] = tsum;
      __syncthreads();
      float msum = 0.f;
      for (int uu = 0; uu < 16; ++uu)
        msum += Mm[i * 16 + r][i * 16 + uu] * Tb[uu][c];
      __syncthreads();
      Mm[i * 16 + r][j * 16 + c] = -msum;
      __syncthreads();
    }
  }

  // stage Q col-major into AM (A is dead)
  {
    const float* mrow = mix + (size_t)(t0g + tr) * 3072 + hk * 64;
#pragma unroll
    for (int e = 0; e < 4; ++e) {
      int c0 = q4 * 16 + e * 4;
      float4 qv = *(const float4*)(mrow + c0);
      AM[c0 + 0][tr] = qv.x; AM[c0 + 1][tr] = qv.y;
      AM[c0 + 2][tr] = qv.z; AM[c0 + 3][tr] = qv.w;
    }
  }
  __syncthreads();

  // P = (QK^T) scaled, masked s<=t -> global
  {
    float acc[16];
#pragma unroll
    for (int i = 0; i < 16; ++i) acc[i] = 0.f;
    for (int d = 0; d < 64; ++d) {
      float qv = AM[d][tr];
#pragma unroll
      for (int e = 0; e < 4; ++e) {
        float4 ks = *(const float4*)&Kt[d][q4 * 16 + e * 4];
        acc[e * 4 + 0] += qv * ks.x; acc[e * 4 + 1] += qv * ks.y;
        acc[e * 4 + 2] += qv * ks.z; acc[e * 4 + 3] += qv * ks.w;
      }
    }
    float ct_ = cs[tr];
#pragma unroll
    for (int e = 0; e < 4; ++e) {
      int s0 = q4 * 16 + e * 4;
      float4 pv;
      pv.x = (s0 + 0 <= tr) ? acc[e * 4 + 0] * __expf(ct_ - cs[s0 + 0]) : 0.f;
      pv.y = (s0 + 1 <= tr) ? acc[e * 4 + 1] * __expf(ct_ - cs[s0 + 1]) : 0.f;
      pv.z = (s0 + 2 <= tr) ? acc[e * 4 + 2] * __expf(ct_ - cs[s0 + 2]) : 0.f;
      pv.w = (s0 + 3 <= tr) ? acc[e * 4 + 3] * __expf(ct_ - cs[s0 + 3]) : 0.f;
      *(float4*)&Pbuf[(size_t)u * 4096 + tr * 64 + s0] = pv;
    }
  }
  __syncthreads();

  // transpose-scale Kt in place: K'[s][k] = Kt_old[k][s] * beta_s * e^{c_s}
  {
    float vals[16];
#pragma unroll
    for (int j = 0; j < 16; ++j) vals[j] = Kt[q4 * 16 + j][tr];
    float sc = bb[tr] * __expf(cs[tr]);
    __syncthreads();
#pragma unroll
    for (int j = 0; j < 16; ++j) Kt[tr][q4 * 16 + j] = vals[j] * sc;
  }
  __syncthreads();

  // W = Mm * K' -> global
  {
    float acc[16];
#pragma unroll
    for (int i = 0; i < 16; ++i) acc[i] = 0.f;
    for (int s = 0; s < 64; ++s) {
      float m = Mm[tr][s];
#pragma unroll
      for (int e = 0; e < 4; ++e) {
        float4 kk = *(const float4*)&Kt[s][q4 * 16 + e * 4];
        acc[e * 4 + 0] += m * kk.x; acc[e * 4 + 1] += m * kk.y;
        acc[e * 4 + 2] += m * kk.z; acc[e * 4 + 3] += m * kk.w;
      }
    }
#pragma unroll
    for (int e = 0; e < 4; ++e) {
      float4 wv = {acc[e * 4 + 0], acc[e * 4 + 1], acc[e * 4 + 2], acc[e * 4 + 3]};
      *(float4*)&Wbuf[(size_t)u * 4096 + tr * 64 + q4 * 16 + e * 4] = wv;
    }
  }
  // R = Mm * (beta .* V) -> global
  {
    float acc[16];
#pragma unroll
    for (int i = 0; i < 16; ++i) acc[i] = 0.f;
    for (int s = 0; s < 64; ++s) {
      float m = Mm[tr][s] * bb[s];
#pragma unroll
      for (int e = 0; e < 4; ++e) {
        float4 vv = *(const float4*)&Vb[s][q4 * 16 + e * 4];
        acc[e * 4 + 0] += m * vv.x; acc[e * 4 + 1] += m * vv.y;
        acc[e * 4 + 2] += m * vv.z; acc[e * 4 + 3] += m * vv.w;
      }
    }
#pragma unroll
    for (int e = 0; e < 4; ++e) {
      float4 rv = {acc[e * 4 + 0], acc[e * 4 + 1], acc[e * 4 + 2], acc[e * 4 + 3]};
      *(float4*)&Rbuf[(size_t)u * 4096 + tr * 64 + q4 * 16 + e * 4] = rv;
    }
  }
}

// ---------------- chunked serial scan ----------------
// 256 blocks = (b, hv, vslice of 16). Per chunk: Delta = R - W*S;
// O = P*Delta + (q e^c)*S; S = e^{c63} S + (K e^{c63-c})^T Delta.
__global__ __launch_bounds__(256) void chunk_scan_kernel(
    const float* __restrict__ mix, const float* __restrict__ Wbuf,
    const float* __restrict__ Pbuf, const float* __restrict__ Rbuf,
    const float* __restrict__ cbuf, float* __restrict__ o) {
  __shared__ float Wb[64][68], Pb[64][68], Kr[64][68], Qr[64][68];
  __shared__ float S[64][16], Db[64][16];
  __shared__ float cs[64], sQ[64], sK[64];

  const int bid = blockIdx.x;
  const int vs = bid & 3, hv = (bid >> 2) & 31, b = bid >> 7;
  const int hk = hv >> 2;
  const int ubase = (b * 32 + hv) * 16;
  const int tid = threadIdx.x;
  const int tr = tid >> 2, q4 = tid & 3;

  ((float4*)S)[tid] = (float4){0.f, 0.f, 0.f, 0.f};

  float4 WN[4], PN[4], KN[4], QN[4], RN;
  float cN = 0.f;

#define ISSUE_LOADS(c)                                                          \
  {                                                                             \
    size_t uu = (size_t)(ubase + (c));                                          \
    _Pragma("unroll") for (int i = 0; i < 4; ++i) {                             \
      WN[i] = ((const float4*)(Wbuf + uu * 4096))[tid + 256 * i];               \
      PN[i] = ((const float4*)(Pbuf + uu * 4096))[tid + 256 * i];               \
    }                                                                           \
    const float* mrow = mix + (size_t)(b * 1024 + (c) * 64 + tr) * 3072;        \
    _Pragma("unroll") for (int e = 0; e < 4; ++e) {                             \
      KN[e] = *(const float4*)(mrow + 512 + hk * 64 + q4 * 16 + e * 4);         \
      QN[e] = *(const float4*)(mrow + hk * 64 + q4 * 16 + e * 4);               \
    }                                                                           \
    RN = *(const float4*)(Rbuf + uu * 4096 + tr * 64 + vs * 16 + q4 * 4);       \
    if (tid < 64) cN = cbuf[uu * 64 + tid];                                     \
  }

#define COMMIT()                                                                \
  {                                                                             \
    _Pragma("unroll") for (int i = 0; i < 4; ++i) {                             \
      int flat = (tid + 256 * i) * 4;                                           \
      int r = flat >> 6, c0 = flat & 63;                                        \
      *(float4*)&Wb[r][c0] = WN[i];                                             \
      *(float4*)&Pb[r][c0] = PN[i];                                             \
    }                                                                           \
    _Pragma("unroll") for (int e = 0; e < 4; ++e) {                             \
      *(float4*)&Kr[tr][q4 * 16 + e * 4] = KN[e];                               \
      *(float4*)&Qr[tr][q4 * 16 + e * 4] = QN[e];                               \
    }                                                                           \
    if (tid < 64) cs[tid] = cN;                                                 \
    __syncthreads();                                                            \
    if (tid < 64) {                                                             \
      sQ[tid] = __expf(cs[tid]);                                                \
      sK[tid] = __expf(cs[63] - cs[tid]);                                       \
    }                                                                           \
    __syncthreads();                                                            \
  }

  ISSUE_LOADS(0);
  COMMIT();
  float4 Rv = RN;

  for (int c = 0; c < 16; ++c) {
    if (c < 15) ISSUE_LOADS(c + 1);
    // GEMM-A: Delta = R - W*S
    float4 acc = Rv;
    for (int k = 0; k < 64; ++k) {
      float w = Wb[tr][k];
      float4 s4 = *(const float4*)&S[k][q4 * 4];
      acc.x -= w * s4.x; acc.y -= w * s4.y; acc.z -= w * s4.z; acc.w -= w * s4.w;
    }
    *(float4*)&Db[tr][q4 * 4] = acc;
    __syncthreads();
    // GEMM-B: O = P*Delta + Qtilde*S
    {
      float sqv = sQ[tr];
      float4 ao = {0.f, 0.f, 0.f, 0.f};
      for (int i = 0; i < 64; ++i) {
        float p = Pb[tr][i];
        float4 d4 = *(const float4*)&Db[i][q4 * 4];
        float qv = Qr[tr][i] * sqv;
        float4 s4 = *(const float4*)&S[i][q4 * 4];
        ao.x += p * d4.x + qv * s4.x; ao.y += p * d4.y + qv * s4.y;
        ao.z += p * d4.z + qv * s4.z; ao.w += p * d4.w + qv * s4.w;
      }
      *(float4*)&o[(size_t)(b * 1024 + c * 64 + tr) * 2048 + hv * 64 + vs * 16 + q4 * 4] = ao;
    }
    __syncthreads();
    // GEMM-C: S = e^{c63} S + Khat^T * Delta
    {
      float e63 = __expf(cs[63]);
      float4 sv = *(const float4*)&S[tr][q4 * 4];
      sv.x *= e63; sv.y *= e63; sv.z *= e63; sv.w *= e63;
      for (int s = 0; s < 64; ++s) {
        float kh = Kr[s][tr] * sK[s];
        float4 d4 = *(const float4*)&Db[s][q4 * 4];
        sv.x += kh * d4.x; sv.y += kh * d4.y; sv.z += kh * d4.z; sv.w += kh * d4.w;
      }
      *(float4*)&S[tr][q4 * 4] = sv;
    }
    __syncthreads();
    if (c < 15) {
      COMMIT();
      Rv = RN;
    }
  }
#undef ISSUE_LOADS
#undef COMMIT
}

// ---------------- rmsnorm * norm_w * silu(z), -> bf16 ----------------
__global__ __launch_bounds__(256) void rms_gate_kernel(const float* __restrict__ o,
                                                       const float* __restrict__ qkvz,
                                                       const float* __restrict__ norm_w,
                                                       short* __restrict__ on) {
  int row = blockIdx.x * 4 + (threadIdx.x >> 6);  // (bt*32+hv) < 65536
  int d = threadIdx.x & 63;
  int hv = row & 31;
  int bt = row >> 5;
  int hk = hv >> 2, vp = hv & 3;
  float x = o[(size_t)row * 64 + d];
  float ss = x * x;
  ss += __shfl_xor(ss, 1);
  ss += __shfl_xor(ss, 2);
  ss += __shfl_xor(ss, 4);
  ss += __shfl_xor(ss, 8);
  ss += __shfl_xor(ss, 16);
  ss += __shfl_xor(ss, 32);
  float sc = rsqrtf(ss * (1.f / 64.f) + 1e-5f);
  float z = qkvz[(size_t)bt * 5184 + hk * 640 + 384 + vp * 64 + d];
  float val = x * sc * norm_w[d] * (z / (1.f + __expf(-z)));
  on[(size_t)row * 64 + d] = f2bf(val);
}

// ---------------- launch ----------------
extern "C" void kernel_launch(void* const* d_in, const int* in_sizes, int n_in,
                              void* d_out, int out_size, void* d_ws, size_t ws_size,
                              hipStream_t stream) {
  const float* hidden = (const float*)d_in[0];
  const float* W_qkvz = (const float*)d_in[1];
  const float* W_ba = (const float*)d_in[2];
  const float* conv_w = (const float*)d_in[3];
  const float* dt_bias = (const float*)d_in[4];
  const float* A_log = (const float*)d_in[5];
  const float* norm_w = (const float*)d_in[6];
  const float* W_out = (const float*)d_in[7];
  float* out = (float*)d_out;

  char* ws = (char*)d_ws;
  short* A_bf = (short*)(ws + 0);                // 16,777,216
  short* Wt1 = (short*)(ws + 16777216);          // 42,467,328  [5184][4096]
  short* Wt2 = (short*)(ws + 59244544);          // 16,777,216  [4096][2048]
  float* qkvz = (float*)(ws + 76021760);         // 42,467,328  [2048][5184]
  float* mix = (float*)(ws + 118489088);         // 25,165,824  [2048][3072]
  float* gbuf = (float*)(ws + 143654912);        //    262,144  [2048][32]
  float* beta = (float*)(ws + 143917056);        //    262,144
  float* o = (float*)(ws + 144179200);           // 16,777,216  [2048][2048]
  short* on = (short*)(ws + 160956416);          //  8,388,608  [2048][2048]
  float* Wbuf = (float*)(ws + 169345024);        // 16,777,216  [1024][64][64]
  float* Pbuf = (float*)(ws + 186122240);        // 16,777,216
  float* Rbuf = (float*)(ws + 202899456);        // 16,777,216
  float* cbuf = (float*)(ws + 219676672);        //    262,144  [1024][64]

  to_bf16_kernel<<<8192, 256, 0, stream>>>(hidden, A_bf);
  transpose_w1<<<dim3(162, 128), 256, 0, stream>>>(W_qkvz, W_ba, Wt1);
  transpose_w2<<<dim3(128, 64), 256, 0, stream>>>(W_out, Wt2);
  gemm_bt<false><<<dim3(32, 81), 256, 0, stream>>>(A_bf, Wt1, qkvz, 2048, 5184, 4096);
  conv_kernel<<<2048, 256, 0, stream>>>(qkvz, conv_w, mix);
  gate_kernel<<<256, 256, 0, stream>>>(qkvz, dt_bias, A_log, gbuf, beta);
  precompute_kernel<<<1024, 256, 0, stream>>>(mix, gbuf, beta, Wbuf, Pbuf, Rbuf, cbuf);
  chunk_scan_kernel<<<256, 256, 0, stream>>>(mix, Wbuf, Pbuf, Rbuf, cbuf, o);
  rms_gate_kernel<<<16384, 256, 0, stream>>>(o, qkvz, norm_w, on);
  gemm_bt<false><<<dim3(32, 64), 256, 0, stream>>>(on, Wt2, out, 2048, 4096, 2048);
}

// Round 4
// 656.259 us; speedup vs baseline: 1.4696x; 1.1195x over previous
//
#include <hip/hip_runtime.h>
#include <hip/hip_bf16.h>
#include <cstdint>
#include <cstddef>

// ---------------- constants ----------------
// B=2 T=1024 H=4096 HK=8 HV=32 DK=64 DV=64 VPK=4
// GEMM1: A[2048][4096] * Wt1[5248(pad 5184)][4096]^T -> qkvz[2048][5184]
// GEMM2: on[2048][2048] * Wt2[4096][2048]^T -> out[2048][4096] (fp32)
// Scan: chunked delta rule, chunk C=64, units = b(2) x hv(32) x chunk(16)

typedef __attribute__((ext_vector_type(8))) short short8;
typedef __attribute__((ext_vector_type(4))) float f32x4;

__device__ __forceinline__ short f2bf(float f) {
  union { float f; unsigned u; } x; x.f = f;
  unsigned r = x.u + 0x7fffu + ((x.u >> 16) & 1u);
  return (short)(r >> 16);
}

__device__ __forceinline__ void gl_lds16(const short* g, short* l) {
  __builtin_amdgcn_global_load_lds(
      (const __attribute__((address_space(1))) void*)g,
      (__attribute__((address_space(3))) void*)l, 16, 0, 0);
}

// ---------------- elementwise fp32 -> bf16 ----------------
__global__ __launch_bounds__(256) void to_bf16_kernel(const float* __restrict__ x,
                                                      short* __restrict__ y) {
  int i = blockIdx.x * 256 + threadIdx.x;   // one float4 per thread
  float4 v = ((const float4*)x)[i];
  ushort4 r;
  r.x = (unsigned short)f2bf(v.x);
  r.y = (unsigned short)f2bf(v.y);
  r.z = (unsigned short)f2bf(v.z);
  r.w = (unsigned short)f2bf(v.w);
  ((ushort4*)y)[i] = r;
}

// ---------------- transpose+convert W_qkvz|W_ba -> Wt1[n][k], pad to 5248 ----------------
__global__ __launch_bounds__(256) void transpose_w1(const float* __restrict__ Wq,
                                                    const float* __restrict__ Wba,
                                                    short* __restrict__ Wt) {
  __shared__ float tile[32][33];
  int n0 = blockIdx.x * 32;  // < 5248
  int k0 = blockIdx.y * 32;  // < 4096
  int t = threadIdx.x;
  int r = t >> 5;    // 0..7
  int c = t & 31;
#pragma unroll
  for (int i = 0; i < 4; ++i) {
    int kl = r + i * 8;
    int n = n0 + c;
    float v = 0.f;
    if (n < 5120) v = Wq[(size_t)(k0 + kl) * 5120 + n];
    else if (n < 5184) v = Wba[(size_t)(k0 + kl) * 64 + (n - 5120)];
    tile[kl][c] = v;
  }
  __syncthreads();
#pragma unroll
  for (int i = 0; i < 4; ++i) {
    int nl = r + i * 8;
    int kl = c;
    Wt[(size_t)(n0 + nl) * 4096 + k0 + kl] = f2bf(tile[kl][nl]);
  }
}

// ---------------- transpose+convert W_out -> Wt2[n][k] ----------------
__global__ __launch_bounds__(256) void transpose_w2(const float* __restrict__ W,
                                                    short* __restrict__ Wt) {
  __shared__ float tile[32][33];
  int n0 = blockIdx.x * 32;  // < 4096
  int k0 = blockIdx.y * 32;  // < 2048
  int t = threadIdx.x;
  int r = t >> 5;
  int c = t & 31;
#pragma unroll
  for (int i = 0; i < 4; ++i) {
    int kl = r + i * 8;
    tile[kl][c] = W[(size_t)(k0 + kl) * 4096 + n0 + c];
  }
  __syncthreads();
#pragma unroll
  for (int i = 0; i < 4; ++i) {
    int nl = r + i * 8;
    int kl = c;
    Wt[(size_t)(n0 + nl) * 2048 + k0 + kl] = f2bf(tile[kl][nl]);
  }
}

// ---------------- m97-style 128x128 bf16 MFMA GEMM, fp32 out ----------------
// C[m][n] = sum_k A[m][k]*Bt[n][k].  4 waves, each owns a 64x64 quadrant
// (4x4 of 16x16x32 MFMA).  Staging via global_load_lds width=16.
template <bool GUARD_N>
__global__ __launch_bounds__(256) void gemm128(const short* __restrict__ A,
                                               const short* __restrict__ Bt,
                                               float* __restrict__ C,
                                               int M, int N, int K) {
  __shared__ __align__(16) short As[128 * 32];
  __shared__ __align__(16) short Bs[128 * 32];
  const int tid = threadIdx.x;
  const int wave = tid >> 6;
  const int lane = tid & 63;
  const int m0 = blockIdx.x * 128;
  const int n0 = blockIdx.y * 128;
  const int wm = (wave >> 1) << 6;
  const int wn = (wave & 1) << 6;

  // staging: round r (0/1): rows r*64 + wave*16 + lane/4, k-elems (lane&3)*8..+8
  const int srow = (wave << 4) + (lane >> 2);
  const int scol = (lane & 3) << 3;
  const short* Ag = A + (size_t)(m0 + srow) * K + scol;
  const short* Bg = Bt + (size_t)(n0 + srow) * K + scol;
  const size_t rstep = (size_t)64 * K;

  const int fr = lane & 15;
  const int kq = (lane >> 4) << 3;

  f32x4 acc[4][4];
#pragma unroll
  for (int i = 0; i < 4; ++i)
#pragma unroll
    for (int j = 0; j < 4; ++j) acc[i][j] = (f32x4){0.f, 0.f, 0.f, 0.f};

  for (int k0 = 0; k0 < K; k0 += 32) {
    __syncthreads();
    gl_lds16(Ag + k0,         &As[wave * 512]);
    gl_lds16(Ag + rstep + k0, &As[2048 + wave * 512]);
    gl_lds16(Bg + k0,         &Bs[wave * 512]);
    gl_lds16(Bg + rstep + k0, &Bs[2048 + wave * 512]);
    __syncthreads();
    short8 af[4], bf[4];
#pragma unroll
    for (int i = 0; i < 4; ++i) {
      af[i] = *(const short8*)&As[(wm + i * 16 + fr) * 32 + kq];
      bf[i] = *(const short8*)&Bs[(wn + i * 16 + fr) * 32 + kq];
    }
#pragma unroll
    for (int mt = 0; mt < 4; ++mt)
#pragma unroll
      for (int nt = 0; nt < 4; ++nt)
        acc[mt][nt] = __builtin_amdgcn_mfma_f32_16x16x32_bf16(af[mt], bf[nt], acc[mt][nt], 0, 0, 0);
  }

  // C/D layout: col = lane&15, row = (lane>>4)*4 + r
  const int rbase = (lane >> 4) << 2;
#pragma unroll
  for (int mt = 0; mt < 4; ++mt) {
#pragma unroll
    for (int nt = 0; nt < 4; ++nt) {
      int ncol = n0 + wn + nt * 16 + fr;
      if (GUARD_N && ncol >= N) continue;
      int mrow = m0 + wm + mt * 16 + rbase;
#pragma unroll
      for (int r = 0; r < 4; ++r)
        C[(size_t)(mrow + r) * N + ncol] = acc[mt][nt][r];
    }
  }
}

// ---------------- conv(4-tap causal) + silu + l2norm(q,k) ----------------
__global__ __launch_bounds__(256) void conv_kernel(const float* __restrict__ qkvz,
                                                   const float* __restrict__ conv_w,
                                                   float* __restrict__ mix) {
  __shared__ float sq[1024];
  __shared__ float scale[16];
  int bt = blockIdx.x;       // b*1024 + t
  int t = bt & 1023;
  int tid = threadIdx.x;
  for (int c = tid; c < 3072; c += 256) {
    int col;
    if (c < 512) {
      col = (c >> 6) * 640 + (c & 63);
    } else if (c < 1024) {
      int c2 = c - 512;
      col = (c2 >> 6) * 640 + 64 + (c2 & 63);
    } else {
      int c3 = c - 1024;
      int hv = c3 >> 6;
      col = (hv >> 2) * 640 + 128 + (hv & 3) * 64 + (c3 & 63);
    }
    float acc = 0.f;
#pragma unroll
    for (int j = 0; j < 4; ++j) {
      int tt = t - 3 + j;
      if (tt >= 0) acc += qkvz[(size_t)(bt - 3 + j) * 5184 + col] * conv_w[c * 4 + j];
    }
    float sv = acc / (1.f + __expf(-acc));  // silu
    if (c < 1024)
      sq[c] = sv;
    else
      mix[(size_t)bt * 3072 + c] = sv;
  }
  __syncthreads();
  int g = tid >> 4, l = tid & 15;
  float p = 0.f;
#pragma unroll
  for (int i = 0; i < 4; ++i) {
    float v = sq[g * 64 + l * 4 + i];
    p += v * v;
  }
  p += __shfl_xor(p, 1);
  p += __shfl_xor(p, 2);
  p += __shfl_xor(p, 4);
  p += __shfl_xor(p, 8);
  if (l == 0) scale[g] = rsqrtf(p + 1e-6f);
  __syncthreads();
  for (int c = tid; c < 1024; c += 256) {
    float s = scale[c >> 6] * ((c < 512) ? 0.125f : 1.f);  // q gets DK^-0.5
    mix[(size_t)bt * 3072 + c] = sq[c] * s;
  }
}

// ---------------- gates: g (log-decay) and beta = sigmoid(b) ----------------
__global__ __launch_bounds__(256) void gate_kernel(const float* __restrict__ qkvz,
                                                   const float* __restrict__ dt_bias,
                                                   const float* __restrict__ A_log,
                                                   float* __restrict__ gb,
                                                   float* __restrict__ beta) {
  int i = blockIdx.x * 256 + threadIdx.x;  // < 65536 = 2048*32
  int hv = i & 31;
  int bt = i >> 5;
  int hk = hv >> 2, vp = hv & 3;
  const float* row = qkvz + (size_t)bt * 5184 + 5120 + hk * 8;
  float bv = row[vp];
  float av = row[4 + vp];
  float x = av + dt_bias[hv];
  float sp = (x > 20.f) ? x : log1pf(expf(x));
  gb[i] = -expf(A_log[hv]) * sp;        // log-decay g_t (<= 0)
  beta[i] = 1.f / (1.f + expf(-bv));
}

// ---------------- chunked delta-rule precompute ----------------
__global__ __launch_bounds__(256) void precompute_kernel(
    const float* __restrict__ mix, const float* __restrict__ gbuf,
    const float* __restrict__ betab, float* __restrict__ Wbuf,
    float* __restrict__ Pbuf, float* __restrict__ Rbuf, float* __restrict__ cbuf) {
  __shared__ float Kt[64][68];   // K col-major: Kt[d][t]; later K' row-major scaled
  __shared__ float Vb[64][68];   // V row-major
  __shared__ float AM[64][68];   // A; later Q col-major
  __shared__ float Mm[64][68];   // (I+A)^{-1}
  __shared__ float Tb[16][17];
  __shared__ float cs[64], bb[64];

  const int u = blockIdx.x;
  const int chunk = u & 15, hv = (u >> 4) & 31, b = u >> 9;
  const int hk = hv >> 2;
  const int t0g = b * 1024 + chunk * 64;
  const int tid = threadIdx.x;
  const int tr = tid >> 2, q4 = tid & 3;

  {
    const float* mrow = mix + (size_t)(t0g + tr) * 3072;
#pragma unroll
    for (int e = 0; e < 4; ++e) {
      int c0 = q4 * 16 + e * 4;
      float4 kv = *(const float4*)(mrow + 512 + hk * 64 + c0);
      Kt[c0 + 0][tr] = kv.x; Kt[c0 + 1][tr] = kv.y;
      Kt[c0 + 2][tr] = kv.z; Kt[c0 + 3][tr] = kv.w;
      *(float4*)&Vb[tr][c0] = *(const float4*)(mrow + 1024 + hv * 64 + c0);
    }
  }
  if (tid < 64) {
    cs[tid] = gbuf[(size_t)(t0g + tid) * 32 + hv];
    bb[tid] = betab[(size_t)(t0g + tid) * 32 + hv];
  }
  __syncthreads();
  for (int off = 1; off < 64; off <<= 1) {
    float v = 0.f;
    if (tid < 64 && tid >= off) v = cs[tid - off];
    __syncthreads();
    if (tid < 64) cs[tid] += v;
    __syncthreads();
  }
  if (tid < 64) cbuf[(size_t)u * 64 + tid] = cs[tid];

  {
    float acc[16];
#pragma unroll
    for (int i = 0; i < 16; ++i) acc[i] = 0.f;
    for (int d = 0; d < 64; ++d) {
      float kv = Kt[d][tr];
#pragma unroll
      for (int e = 0; e < 4; ++e) {
        float4 ks = *(const float4*)&Kt[d][q4 * 16 + e * 4];
        acc[e * 4 + 0] += kv * ks.x; acc[e * 4 + 1] += kv * ks.y;
        acc[e * 4 + 2] += kv * ks.z; acc[e * 4 + 3] += kv * ks.w;
      }
    }
    float bt_ = bb[tr], ct_ = cs[tr];
#pragma unroll
    for (int j = 0; j < 16; ++j) {
      int s = q4 * 16 + j;
      AM[tr][s] = (s < tr) ? bt_ * acc[j] * __expf(ct_ - cs[s]) : 0.f;
    }
  }
  __syncthreads();

  for (int i = tid; i < 64 * 68; i += 256) (&Mm[0][0])[i] = 0.f;
  __syncthreads();
  if (tid < 64) {
    int blk = tid >> 4, j = tid & 15, base = blk * 16;
    Mm[base][base + j] = (j == 0) ? 1.f : 0.f;
    for (int r = 1; r < 16; ++r) {
      float sum = 0.f;
      for (int s = 0; s < r; ++s) sum += AM[base + r][base + s] * Mm[base + s][base + j];
      Mm[base + r][base + j] = ((r == j) ? 1.f : 0.f) - sum;
    }
  }
  __syncthreads();
  for (int d = 1; d < 4; ++d) {
    for (int j = 0; j + d < 4; ++j) {
      int i = j + d;
      int r = tid >> 4, c = tid & 15;
      float tsum = 0.f;
      for (int kb = j; kb < i; ++kb)
        for (int uu = 0; uu < 16; ++uu)
          tsum += AM[i * 16 + r][kb * 16 + uu] * Mm[kb * 16 + uu][j * 16 + c];
      Tb[r][c] = tsum;
      __syncthreads();
      float msum = 0.f;
      for (int uu = 0; uu < 16; ++uu)
        msum += Mm[i * 16 + r][i * 16 + uu] * Tb[uu][c];
      __syncthreads();
      Mm[i * 16 + r][j * 16 + c] = -msum;
      __syncthreads();
    }
  }

  {
    const float* mrow = mix + (size_t)(t0g + tr) * 3072 + hk * 64;
#pragma unroll
    for (int e = 0; e < 4; ++e) {
      int c0 = q4 * 16 + e * 4;
      float4 qv = *(const float4*)(mrow + c0);
      AM[c0 + 0][tr] = qv.x; AM[c0 + 1][tr] = qv.y;
      AM[c0 + 2][tr] = qv.z; AM[c0 + 3][tr] = qv.w;
    }
  }
  __syncthreads();

  {
    float acc[16];
#pragma unroll
    for (int i = 0; i < 16; ++i) acc[i] = 0.f;
    for (int d = 0; d < 64; ++d) {
      float qv = AM[d][tr];
#pragma unroll
      for (int e = 0; e < 4; ++e) {
        float4 ks = *(const float4*)&Kt[d][q4 * 16 + e * 4];
        acc[e * 4 + 0] += qv * ks.x; acc[e * 4 + 1] += qv * ks.y;
        acc[e * 4 + 2] += qv * ks.z; acc[e * 4 + 3] += qv * ks.w;
      }
    }
    float ct_ = cs[tr];
#pragma unroll
    for (int e = 0; e < 4; ++e) {
      int s0 = q4 * 16 + e * 4;
      float4 pv;
      pv.x = (s0 + 0 <= tr) ? acc[e * 4 + 0] * __expf(ct_ - cs[s0 + 0]) : 0.f;
      pv.y = (s0 + 1 <= tr) ? acc[e * 4 + 1] * __expf(ct_ - cs[s0 + 1]) : 0.f;
      pv.z = (s0 + 2 <= tr) ? acc[e * 4 + 2] * __expf(ct_ - cs[s0 + 2]) : 0.f;
      pv.w = (s0 + 3 <= tr) ? acc[e * 4 + 3] * __expf(ct_ - cs[s0 + 3]) : 0.f;
      *(float4*)&Pbuf[(size_t)u * 4096 + tr * 64 + s0] = pv;
    }
  }
  __syncthreads();

  {
    float vals[16];
#pragma unroll
    for (int j = 0; j < 16; ++j) vals[j] = Kt[q4 * 16 + j][tr];
    float sc = bb[tr] * __expf(cs[tr]);
    __syncthreads();
#pragma unroll
    for (int j = 0; j < 16; ++j) Kt[tr][q4 * 16 + j] = vals[j] * sc;
  }
  __syncthreads();

  {
    float acc[16];
#pragma unroll
    for (int i = 0; i < 16; ++i) acc[i] = 0.f;
    for (int s = 0; s < 64; ++s) {
      float m = Mm[tr][s];
#pragma unroll
      for (int e = 0; e < 4; ++e) {
        float4 kk = *(const float4*)&Kt[s][q4 * 16 + e * 4];
        acc[e * 4 + 0] += m * kk.x; acc[e * 4 + 1] += m * kk.y;
        acc[e * 4 + 2] += m * kk.z; acc[e * 4 + 3] += m * kk.w;
      }
    }
#pragma unroll
    for (int e = 0; e < 4; ++e) {
      float4 wv = {acc[e * 4 + 0], acc[e * 4 + 1], acc[e * 4 + 2], acc[e * 4 + 3]};
      *(float4*)&Wbuf[(size_t)u * 4096 + tr * 64 + q4 * 16 + e * 4] = wv;
    }
  }
  {
    float acc[16];
#pragma unroll
    for (int i = 0; i < 16; ++i) acc[i] = 0.f;
    for (int s = 0; s < 64; ++s) {
      float m = Mm[tr][s] * bb[s];
#pragma unroll
      for (int e = 0; e < 4; ++e) {
        float4 vv = *(const float4*)&Vb[s][q4 * 16 + e * 4];
        acc[e * 4 + 0] += m * vv.x; acc[e * 4 + 1] += m * vv.y;
        acc[e * 4 + 2] += m * vv.z; acc[e * 4 + 3] += m * vv.w;
      }
    }
#pragma unroll
    for (int e = 0; e < 4; ++e) {
      float4 rv = {acc[e * 4 + 0], acc[e * 4 + 1], acc[e * 4 + 2], acc[e * 4 + 3]};
      *(float4*)&Rbuf[(size_t)u * 4096 + tr * 64 + q4 * 16 + e * 4] = rv;
    }
  }
}

// ---------------- chunked serial scan ----------------
__global__ __launch_bounds__(256) void chunk_scan_kernel(
    const float* __restrict__ mix, const float* __restrict__ Wbuf,
    const float* __restrict__ Pbuf, const float* __restrict__ Rbuf,
    const float* __restrict__ cbuf, float* __restrict__ o) {
  __shared__ float Wb[64][68], Pb[64][68], Kr[64][68], Qr[64][68];
  __shared__ float S[64][16], Db[64][16];
  __shared__ float cs[64], sQ[64], sK[64];

  const int bid = blockIdx.x;
  const int vs = bid & 3, hv = (bid >> 2) & 31, b = bid >> 7;
  const int hk = hv >> 2;
  const int ubase = (b * 32 + hv) * 16;
  const int tid = threadIdx.x;
  const int tr = tid >> 2, q4 = tid & 3;

  ((float4*)S)[tid] = (float4){0.f, 0.f, 0.f, 0.f};

  float4 WN[4], PN[4], KN[4], QN[4], RN;
  float cN = 0.f;

#define ISSUE_LOADS(c)                                                          \
  {                                                                             \
    size_t uu = (size_t)(ubase + (c));                                          \
    _Pragma("unroll") for (int i = 0; i < 4; ++i) {                             \
      WN[i] = ((const float4*)(Wbuf + uu * 4096))[tid + 256 * i];               \
      PN[i] = ((const float4*)(Pbuf + uu * 4096))[tid + 256 * i];               \
    }                                                                           \
    const float* mrow = mix + (size_t)(b * 1024 + (c) * 64 + tr) * 3072;        \
    _Pragma("unroll") for (int e = 0; e < 4; ++e) {                             \
      KN[e] = *(const float4*)(mrow + 512 + hk * 64 + q4 * 16 + e * 4);         \
      QN[e] = *(const float4*)(mrow + hk * 64 + q4 * 16 + e * 4);               \
    }                                                                           \
    RN = *(const float4*)(Rbuf + uu * 4096 + tr * 64 + vs * 16 + q4 * 4);       \
    if (tid < 64) cN = cbuf[uu * 64 + tid];                                     \
  }

#define COMMIT()                                                                \
  {                                                                             \
    _Pragma("unroll") for (int i = 0; i < 4; ++i) {                             \
      int flat = (tid + 256 * i) * 4;                                           \
      int r = flat >> 6, c0 = flat & 63;                                        \
      *(float4*)&Wb[r][c0] = WN[i];                                             \
      *(float4*)&Pb[r][c0] = PN[i];                                             \
    }                                                                           \
    _Pragma("unroll") for (int e = 0; e < 4; ++e) {                             \
      *(float4*)&Kr[tr][q4 * 16 + e * 4] = KN[e];                               \
      *(float4*)&Qr[tr][q4 * 16 + e * 4] = QN[e];                               \
    }                                                                           \
    if (tid < 64) cs[tid] = cN;                                                 \
    __syncthreads();                                                            \
    if (tid < 64) {                                                             \
      sQ[tid] = __expf(cs[tid]);                                                \
      sK[tid] = __expf(cs[63] - cs[tid]);                                       \
    }                                                                           \
    __syncthreads();                                                            \
  }

  ISSUE_LOADS(0);
  COMMIT();
  float4 Rv = RN;

  for (int c = 0; c < 16; ++c) {
    if (c < 15) ISSUE_LOADS(c + 1);
    float4 acc = Rv;
    for (int k = 0; k < 64; ++k) {
      float w = Wb[tr][k];
      float4 s4 = *(const float4*)&S[k][q4 * 4];
      acc.x -= w * s4.x; acc.y -= w * s4.y; acc.z -= w * s4.z; acc.w -= w * s4.w;
    }
    *(float4*)&Db[tr][q4 * 4] = acc;
    __syncthreads();
    {
      float sqv = sQ[tr];
      float4 ao = {0.f, 0.f, 0.f, 0.f};
      for (int i = 0; i < 64; ++i) {
        float p = Pb[tr][i];
        float4 d4 = *(const float4*)&Db[i][q4 * 4];
        float qv = Qr[tr][i] * sqv;
        float4 s4 = *(const float4*)&S[i][q4 * 4];
        ao.x += p * d4.x + qv * s4.x; ao.y += p * d4.y + qv * s4.y;
        ao.z += p * d4.z + qv * s4.z; ao.w += p * d4.w + qv * s4.w;
      }
      *(float4*)&o[(size_t)(b * 1024 + c * 64 + tr) * 2048 + hv * 64 + vs * 16 + q4 * 4] = ao;
    }
    __syncthreads();
    {
      float e63 = __expf(cs[63]);
      float4 sv = *(const float4*)&S[tr][q4 * 4];
      sv.x *= e63; sv.y *= e63; sv.z *= e63; sv.w *= e63;
      for (int s = 0; s < 64; ++s) {
        float kh = Kr[s][tr] * sK[s];
        float4 d4 = *(const float4*)&Db[s][q4 * 4];
        sv.x += kh * d4.x; sv.y += kh * d4.y; sv.z += kh * d4.z; sv.w += kh * d4.w;
      }
      *(float4*)&S[tr][q4 * 4] = sv;
    }
    __syncthreads();
    if (c < 15) {
      COMMIT();
      Rv = RN;
    }
  }
#undef ISSUE_LOADS
#undef COMMIT
}

// ---------------- rmsnorm * norm_w * silu(z), -> bf16 ----------------
__global__ __launch_bounds__(256) void rms_gate_kernel(const float* __restrict__ o,
                                                       const float* __restrict__ qkvz,
                                                       const float* __restrict__ norm_w,
                                                       short* __restrict__ on) {
  int row = blockIdx.x * 4 + (threadIdx.x >> 6);  // (bt*32+hv) < 65536
  int d = threadIdx.x & 63;
  int hv = row & 31;
  int bt = row >> 5;
  int hk = hv >> 2, vp = hv & 3;
  float x = o[(size_t)row * 64 + d];
  float ss = x * x;
  ss += __shfl_xor(ss, 1);
  ss += __shfl_xor(ss, 2);
  ss += __shfl_xor(ss, 4);
  ss += __shfl_xor(ss, 8);
  ss += __shfl_xor(ss, 16);
  ss += __shfl_xor(ss, 32);
  float sc = rsqrtf(ss * (1.f / 64.f) + 1e-5f);
  float z = qkvz[(size_t)bt * 5184 + hk * 640 + 384 + vp * 64 + d];
  float val = x * sc * norm_w[d] * (z / (1.f + __expf(-z)));
  on[(size_t)row * 64 + d] = f2bf(val);
}

// ---------------- launch ----------------
extern "C" void kernel_launch(void* const* d_in, const int* in_sizes, int n_in,
                              void* d_out, int out_size, void* d_ws, size_t ws_size,
                              hipStream_t stream) {
  const float* hidden = (const float*)d_in[0];
  const float* W_qkvz = (const float*)d_in[1];
  const float* W_ba = (const float*)d_in[2];
  const float* conv_w = (const float*)d_in[3];
  const float* dt_bias = (const float*)d_in[4];
  const float* A_log = (const float*)d_in[5];
  const float* norm_w = (const float*)d_in[6];
  const float* W_out = (const float*)d_in[7];
  float* out = (float*)d_out;

  char* ws = (char*)d_ws;
  short* A_bf = (short*)(ws + 0);                // 16,777,216
  short* Wt1 = (short*)(ws + 16777216);          // 42,991,616  [5248][4096] (pad)
  short* Wt2 = (short*)(ws + 59768832);          // 16,777,216  [4096][2048]
  float* qkvz = (float*)(ws + 76546048);         // 42,467,328  [2048][5184]
  float* mix = (float*)(ws + 119013376);         // 25,165,824  [2048][3072]
  float* gbuf = (float*)(ws + 144179200);        //    262,144  [2048][32]
  float* beta = (float*)(ws + 144441344);        //    262,144
  float* o = (float*)(ws + 144703488);           // 16,777,216  [2048][2048]
  short* on = (short*)(ws + 161480704);          //  8,388,608  [2048][2048]
  float* Wbuf = (float*)(ws + 169869312);        // 16,777,216  [1024][64][64]
  float* Pbuf = (float*)(ws + 186646528);        // 16,777,216
  float* Rbuf = (float*)(ws + 203423744);        // 16,777,216
  float* cbuf = (float*)(ws + 220200960);        //    262,144  [1024][64]

  to_bf16_kernel<<<8192, 256, 0, stream>>>(hidden, A_bf);
  transpose_w1<<<dim3(164, 128), 256, 0, stream>>>(W_qkvz, W_ba, Wt1);
  transpose_w2<<<dim3(128, 64), 256, 0, stream>>>(W_out, Wt2);
  gemm128<true><<<dim3(16, 41), 256, 0, stream>>>(A_bf, Wt1, qkvz, 2048, 5184, 4096);
  conv_kernel<<<2048, 256, 0, stream>>>(qkvz, conv_w, mix);
  gate_kernel<<<256, 256, 0, stream>>>(qkvz, dt_bias, A_log, gbuf, beta);
  precompute_kernel<<<1024, 256, 0, stream>>>(mix, gbuf, beta, Wbuf, Pbuf, Rbuf, cbuf);
  chunk_scan_kernel<<<256, 256, 0, stream>>>(mix, Wbuf, Pbuf, Rbuf, cbuf, o);
  rms_gate_kernel<<<16384, 256, 0, stream>>>(o, qkvz, norm_w, on);
  gemm128<false><<<dim3(16, 32), 256, 0, stream>>>(on, Wt2, out, 2048, 4096, 2048);
}